// Round 5
// baseline (316.258 us; speedup 1.0000x reference)
//
#include <hip/hip_runtime.h>
#include <hip/hip_bf16.h>

// Transformer block fwd: B=2, T=2048, C=1024, H=16, D=64.
// out = concat(x_out fp32 [2,2048,1024], k fp32 [2,16,2048,64], v fp32 [2,16,2048,64])

#define T_SEQ 2048
#define C_DIM 1024
#define HEADS 16
#define HD    64

typedef __attribute__((ext_vector_type(8))) short s16x8;   // 8 x bf16 (4 VGPR) — MFMA A/B frag
typedef __attribute__((ext_vector_type(4))) short s16x4;
typedef __attribute__((ext_vector_type(4))) float f32x4;   // MFMA C/D frag

__device__ __forceinline__ short f2bf(float f) {
    union { __hip_bfloat16 h; short s; } u;
    u.h = __float2bfloat16(f);
    return u.s;
}

// async global->LDS, 16B per lane. LDS dest = wave-uniform base + lane*16 (linear).
__device__ __forceinline__ void gload16(const void* g, void* l) {
    __builtin_amdgcn_global_load_lds(
        (const __attribute__((address_space(1))) void*)g,
        (__attribute__((address_space(3))) void*)l, 16, 0, 0);
}
#define VMCNT0 asm volatile("s_waitcnt vmcnt(0)" ::: "memory")
#define BARRAW asm volatile("s_barrier" ::: "memory")
#define PRIO1  __builtin_amdgcn_s_setprio(1)
#define PRIO0  __builtin_amdgcn_s_setprio(0)

template<int N> __device__ __forceinline__ void vmcnt_n() {
    asm volatile("s_waitcnt vmcnt(%0)" :: "n"(N) : "memory");
}

// ---------------- weight transpose + cast: W[K][N] fp32 -> Wt[N][K] bf16 ----------------
__global__ __launch_bounds__(256) void transpose_cast_kernel(
    const float* __restrict__ W, short* __restrict__ Wt, int K, int N) {
    __shared__ float t[32][33];
    int n0 = blockIdx.x * 32, k0 = blockIdx.y * 32;
    int tx = threadIdx.x, ty = threadIdx.y;
#pragma unroll
    for (int i = 0; i < 4; i++) t[ty + 8 * i][tx] = W[(k0 + ty + 8 * i) * N + n0 + tx];
    __syncthreads();
#pragma unroll
    for (int i = 0; i < 4; i++) Wt[(n0 + ty + 8 * i) * K + k0 + tx] = f2bf(t[tx][ty + 8 * i]);
}

// ---------------- LayerNorm: one block per row of [4096][1024], bf16 out ----------------
__global__ __launch_bounds__(256) void ln_kernel(
    const float* __restrict__ x, const float* __restrict__ w, const float* __restrict__ b,
    short* __restrict__ out) {
    int row = blockIdx.x, tid = threadIdx.x;
    float4 v = ((const float4*)(x + row * C_DIM))[tid];
    float s  = v.x + v.y + v.z + v.w;
    float sq = v.x * v.x + v.y * v.y + v.z * v.z + v.w * v.w;
#pragma unroll
    for (int off = 32; off > 0; off >>= 1) {
        s  += __shfl_down(s, off, 64);
        sq += __shfl_down(sq, off, 64);
    }
    __shared__ float rs[4], rq[4];
    int wv = tid >> 6, ln = tid & 63;
    if (ln == 0) { rs[wv] = s; rq[wv] = sq; }
    __syncthreads();
    s = rs[0] + rs[1] + rs[2] + rs[3];
    sq = rq[0] + rq[1] + rq[2] + rq[3];
    float mean = s * (1.f / C_DIM);
    float rstd = rsqrtf(sq * (1.f / C_DIM) - mean * mean + 1e-5f);
    float4 wv4 = ((const float4*)w)[tid];
    float4 bv4 = ((const float4*)b)[tid];
    s16x4 o;
    o[0] = f2bf((v.x - mean) * rstd * wv4.x + bv4.x);
    o[1] = f2bf((v.y - mean) * rstd * wv4.y + bv4.y);
    o[2] = f2bf((v.z - mean) * rstd * wv4.z + bv4.z);
    o[3] = f2bf((v.w - mean) * rstd * wv4.w + bv4.w);
    *(s16x4*)(out + row * C_DIM + tid * 4) = o;
}

// ---------------- residual + LayerNorm: x1 = x + y (fp32 out), h2 = LN(x1) bf16 ----------------
__global__ __launch_bounds__(256) void resln_kernel(
    const float* __restrict__ x, const float* __restrict__ y,
    const float* __restrict__ w, const float* __restrict__ b,
    float* __restrict__ x1, short* __restrict__ out) {
    int row = blockIdx.x, tid = threadIdx.x;
    float4 vx = ((const float4*)(x + row * C_DIM))[tid];
    float4 vy = ((const float4*)(y + row * C_DIM))[tid];
    float4 v;
    v.x = vx.x + vy.x; v.y = vx.y + vy.y; v.z = vx.z + vy.z; v.w = vx.w + vy.w;
    ((float4*)(x1 + row * C_DIM))[tid] = v;
    float s  = v.x + v.y + v.z + v.w;
    float sq = v.x * v.x + v.y * v.y + v.z * v.z + v.w * v.w;
#pragma unroll
    for (int off = 32; off > 0; off >>= 1) {
        s  += __shfl_down(s, off, 64);
        sq += __shfl_down(sq, off, 64);
    }
    __shared__ float rs[4], rq[4];
    int wv = tid >> 6, ln = tid & 63;
    if (ln == 0) { rs[wv] = s; rq[wv] = sq; }
    __syncthreads();
    s = rs[0] + rs[1] + rs[2] + rs[3];
    sq = rq[0] + rq[1] + rq[2] + rq[3];
    float mean = s * (1.f / C_DIM);
    float rstd = rsqrtf(sq * (1.f / C_DIM) - mean * mean + 1e-5f);
    float4 wv4 = ((const float4*)w)[tid];
    float4 bv4 = ((const float4*)b)[tid];
    s16x4 o;
    o[0] = f2bf((v.x - mean) * rstd * wv4.x + bv4.x);
    o[1] = f2bf((v.y - mean) * rstd * wv4.y + bv4.y);
    o[2] = f2bf((v.z - mean) * rstd * wv4.z + bv4.z);
    o[3] = f2bf((v.w - mean) * rstd * wv4.w + bv4.w);
    *(s16x4*)(out + row * C_DIM + tid * 4) = o;
}

// ---------------- phase-interleaved GEMM with counted-vmcnt cascade (T3+T4) ----------------
// C[M,N] = A[M,K](bf16) @ Bt[N,K]^T(bf16) + bias, fused epilogues. BK=64, 8 waves (WMGxWNG),
// 512 threads, double-buffered LDS. 4 phases per K-tile (quadrants 00,10,11,01); each phase:
// {ds_read subtile | issue gload_lds half-tile(s) of tile t+1 -> s_barrier -> MFMA -> counted
// vmcnt -> s_barrier}. Staging calendar: P1: A0+B0, P2: A1, P3: B1 (>=3 phases slack each).
// Waits (R = gload rounds per half-tile): after P1/P2: vmcnt(3R); after P4: vmcnt(2R); NEVER 0
// in main loop. Last tile peels 2R -> R -> 0.
// Race ledger: half X_{t+1} staged in t.Pk writes a region whose last reader (tile t-1) finished
// before the trailing barrier of t-1.P4 < issue point; all reads of buf[cur] complete before the
// mid-barrier of their phase (compiler lgkmcnt on data-dep).
// MODE 0: fused QKV; MODE 1: FC+GELU; MODE 2: PROJ + bias + residual.
template<int BM, int BN, int WMG, int WNG, int MODE>
__global__ __launch_bounds__(WMG * WNG * 64, 2) void gemm_kp(
    const short* __restrict__ A, const short* __restrict__ Bt, int K, int N,
    const float* __restrict__ b0, const float* __restrict__ b1, const float* __restrict__ b2,
    short* __restrict__ os0, short* __restrict__ os1, short* __restrict__ os2,
    float* __restrict__ of0, float* __restrict__ of1, const float* __restrict__ extra) {
    constexpr int THREADS = WMG * WNG * 64;
    constexpr int R = (BM * 64) / (16 * THREADS);   // gload rounds per half-tile (BM==BN)
    constexpr int RROWS = THREADS / 8;              // rows covered per gload round
    constexpr int WTM = BM / WMG, WTN = BN / WNG;
    constexpr int MFR = WTM / 16, NFR = WTN / 16;
    constexpr int MH = MFR / 2, NH = NFR / 2;

    __shared__ short As[2][BM * 64];
    __shared__ short Bs[2][BN * 64];

    const int tid = threadIdx.x;
    const int wv = tid >> 6, lane = tid & 63, g = lane >> 4, r4 = lane & 15;
    const int wm = wv / WNG, wn = wv % WNG;
    const int lr = lane >> 3, lc = lane & 7, sc = lc ^ lr;

    const int nwg = gridDim.x * gridDim.y;
    const int bid = blockIdx.y * gridDim.x + blockIdx.x;
    const int swz = (bid & 7) * (nwg >> 3) + (bid >> 3);   // bijective, nwg % 8 == 0
    const int m0 = (swz % gridDim.x) * BM, n0 = (swz / gridDim.x) * BN;

    const size_t aoff = (size_t)m0 * K + sc * 8;
    const size_t boff = (size_t)n0 * K + sc * 8;

    const f32x4 zero4 = {0.f, 0.f, 0.f, 0.f};
    f32x4 acc[MFR][NFR];
#pragma unroll
    for (int i = 0; i < MFR; i++)
#pragma unroll
        for (int j = 0; j < NFR; j++) acc[i][j] = zero4;

    s16x8 aF[MH][2], bF[NH][2];

    // staging: half h of K-tile t1 into buffer bb
    auto stA = [&](int bb, int t1, int h) {
#pragma unroll
        for (int j = 0; j < R; j++) {
            int rbase = h * (BM / 2) + j * RROWS + wv * 8;
            gload16(A + aoff + (size_t)(rbase + lr) * K + (size_t)t1 * 64, &As[bb][rbase * 64]);
        }
    };
    auto stB = [&](int bb, int t1, int h) {
#pragma unroll
        for (int j = 0; j < R; j++) {
            int rbase = h * (BN / 2) + j * RROWS + wv * 8;
            gload16(Bt + boff + (size_t)(rbase + lr) * K + (size_t)t1 * 64, &Bs[bb][rbase * 64]);
        }
    };
    auto ldA = [&](const char* Ac, int h) {
#pragma unroll
        for (int mf = 0; mf < MH; mf++) {
            int row = wm * WTM + (h * MH + mf) * 16 + r4;
#pragma unroll
            for (int kk = 0; kk < 2; kk++)
                aF[mf][kk] = *(const s16x8*)(Ac + ((row * 128 + kk * 64 + g * 16) ^ ((row & 7) << 4)));
        }
    };
    auto ldB = [&](const char* Bc, int h) {
#pragma unroll
        for (int nf = 0; nf < NH; nf++) {
            int row = wn * WTN + (h * NH + nf) * 16 + r4;
#pragma unroll
            for (int kk = 0; kk < 2; kk++)
                bF[nf][kk] = *(const s16x8*)(Bc + ((row * 128 + kk * 64 + g * 16) ^ ((row & 7) << 4)));
        }
    };

#define MMQ(QM, QN)                                                                  \
    PRIO1;                                                                           \
    _Pragma("unroll")                                                                \
    for (int mf = 0; mf < MH; mf++)                                                  \
        _Pragma("unroll")                                                            \
        for (int nf = 0; nf < NH; nf++)                                              \
            _Pragma("unroll")                                                        \
            for (int kk = 0; kk < 2; kk++)                                           \
                acc[(QM) * MH + mf][(QN) * NH + nf] =                                \
                    __builtin_amdgcn_mfma_f32_16x16x32_bf16(                         \
                        aF[mf][kk], bF[nf][kk], acc[(QM) * MH + mf][(QN) * NH + nf], \
                        0, 0, 0);                                                    \
    PRIO0;

    // prologue: stage K-tile 0 fully into buffer 0, drain, barrier
    stA(0, 0, 0); stB(0, 0, 0); stA(0, 0, 1); stB(0, 0, 1);
    VMCNT0;
    BARRAW;

    const int NT = K >> 6;
    for (int t = 0; t < NT; ++t) {
        const int c = t & 1, bb = c ^ 1;
        const bool st = (t + 1 < NT);
        const char* Ac = (const char*)&As[c][0];
        const char* Bc = (const char*)&Bs[c][0];

        // phase 1: read B0 + A0; stage (t+1).A0 + (t+1).B0
        ldB(Bc, 0);
        ldA(Ac, 0);
        if (st) { stA(bb, t + 1, 0); stB(bb, t + 1, 0); }
        BARRAW;
        MMQ(0, 0);
        if (st) vmcnt_n<3 * R>(); else vmcnt_n<R>();
        BARRAW;

        // phase 2: read A1; stage (t+1).A1
        ldA(Ac, 1);
        if (st) stA(bb, t + 1, 1);
        BARRAW;
        MMQ(1, 0);
        if (st) vmcnt_n<3 * R>(); else vmcnt_n<0>();
        BARRAW;

        // phase 3: read B1; stage (t+1).B1   (aF half1 held in regs)
        ldB(Bc, 1);
        if (st) stB(bb, t + 1, 1);
        BARRAW;
        MMQ(1, 1);
        BARRAW;

        // phase 4: re-read A0   (bF half1 held in regs)
        ldA(Ac, 0);
        BARRAW;
        MMQ(0, 1);
        if (st) vmcnt_n<2 * R>();
        BARRAW;
    }
#undef MMQ

    // epilogue: D layout col = lane&15, row = 4*(lane>>4)+r  [verified m89/m91]
#pragma unroll
    for (int mf = 0; mf < MFR; mf++) {
#pragma unroll
        for (int nf = 0; nf < NFR; nf++) {
            int n = n0 + wn * WTN + nf * 16 + r4;
#pragma unroll
            for (int r = 0; r < 4; r++) {
                int m = m0 + wm * WTM + mf * 16 + 4 * g + r;
                float val = acc[mf][nf][r];
                if constexpr (MODE == 0) {
                    int sel = n >> 10, nn = n & 1023;
                    const float* bp = (sel == 0) ? b0 : ((sel == 1) ? b1 : b2);
                    val += bp[nn];
                    int bb2 = m >> 11, tt = m & 2047, h = nn >> 6, d = nn & 63;
                    int qi = ((bb2 * HEADS + h) * T_SEQ + tt) * HD + d;
                    if (sel == 0) {
                        os0[qi] = f2bf(val);
                    } else if (sel == 1) {
                        os1[qi] = f2bf(val);
                        of0[qi] = val;
                    } else {
                        of1[qi] = val;
                        os2[((bb2 * HEADS + h) * HD + d) * T_SEQ + tt] = f2bf(val);
                    }
                } else if constexpr (MODE == 1) {
                    val += b0[n];
                    val = 0.5f * val * (1.f + erff(val * 0.70710678118f));  // exact GELU
                    os0[m * N + n] = f2bf(val);
                } else {
                    val += b0[n];
                    of0[m * N + n] = val + extra[m * N + n];
                }
            }
        }
    }
}

// ---------------- causal flash attention (swapped QK^T, lane-local softmax) ----------------
// grid (32, 32); qtr = 31 - blockIdx.x (heavy blocks dispatch first). 4 waves x 16 q-rows,
// KV tile = 64. K [T,D] and V^T [D,T] staged via global_load_lds (pre-swizzled source),
// double-buffered, ONE barrier per tile. S^T = mfma(K, Q): lane owns q = lane&15, holds
// 16 kv values in-register -> softmax = in-lane reduce + 2 shfl_xor.
__global__ __launch_bounds__(256) void attn_kernel(
    const short* __restrict__ qb, const short* __restrict__ kb,
    const short* __restrict__ vtb, float* __restrict__ y) {
    __shared__ short Ks[2][64 * 64];
    __shared__ short Vs[2][64 * 64];
    __shared__ short Ps[4][16 * 64];
    int qtr = (gridDim.x - 1) - blockIdx.x;
    int bh = blockIdx.y;
    int tid = threadIdx.x, w = tid >> 6, lane = tid & 63, g = lane >> 4, r4 = lane & 15;
    int qbase = qtr * 64;
    int lr = lane >> 3, lc = lane & 7, sc = lc ^ lr;   // pre-swizzled source chunk

    // Q B-frags (lane's q = r4): Q[qbase + w*16 + r4][kk*32 + g*8 + j]
    const short* Qp = qb + ((size_t)bh * T_SEQ + qbase + w * 16 + r4) * HD;
    s16x8 qf0 = *(const s16x8*)&Qp[g * 8];
    s16x8 qf1 = *(const s16x8*)&Qp[32 + g * 8];

    const f32x4 zero4 = {0.f, 0.f, 0.f, 0.f};
    f32x4 yacc[4];
#pragma unroll
    for (int ni = 0; ni < 4; ni++) yacc[ni] = zero4;
    float mrun = -1e30f, lrun = 0.f;

    // stage tile 0 into buf 0
#pragma unroll
    for (int j = 0; j < 2; j++) {
        int rw = (w * 2 + j) * 8 + lr;
        gload16(kb  + ((size_t)bh * T_SEQ + rw) * HD + sc * 8, &Ks[0][(w * 2 + j) * 512]);
        gload16(vtb + ((size_t)bh * HD + rw) * T_SEQ + sc * 8, &Vs[0][(w * 2 + j) * 512]);
    }
    VMCNT0;
    __syncthreads();

    int nst = qtr + 1;
    for (int st = 0; st < nst; ++st) {
        int cur = st & 1;
        int s0 = st * 64;
        if (st + 1 < nst) {   // prefetch next tile into other buffer (async, no wait)
#pragma unroll
            for (int j = 0; j < 2; j++) {
                int rw = (w * 2 + j) * 8 + lr;
                gload16(kb  + ((size_t)bh * T_SEQ + s0 + 64 + rw) * HD + sc * 8,
                        &Ks[cur ^ 1][(w * 2 + j) * 512]);
                gload16(vtb + ((size_t)bh * HD + rw) * T_SEQ + s0 + 64 + sc * 8,
                        &Vs[cur ^ 1][(w * 2 + j) * 512]);
            }
        }
        // ---- S^T = K Q^T : sacc[sb] rows kv = sb*16+4g+r, col q = r4
        f32x4 sacc[4];
#pragma unroll
        for (int sb = 0; sb < 4; sb++) sacc[sb] = zero4;
#pragma unroll
        for (int kk = 0; kk < 2; kk++) {
            s16x8 qf = (kk == 0) ? qf0 : qf1;
#pragma unroll
            for (int sb = 0; sb < 4; sb++) {
                int srow = sb * 16 + r4;
                s16x8 kf = *(const s16x8*)((const char*)&Ks[cur][0] +
                            ((srow * 128 + kk * 64 + g * 16) ^ ((r4 & 7) << 4)));
                sacc[sb] = __builtin_amdgcn_mfma_f32_16x16x32_bf16(kf, qf, sacc[sb], 0, 0, 0);
            }
        }
        // ---- online softmax: lane owns q = qbase + w*16 + r4, 16 kv values in-register
        bool diag = (st == qtr);
        float p[4][4];
        float mx = -1e30f;
#pragma unroll
        for (int sb = 0; sb < 4; sb++)
#pragma unroll
            for (int r = 0; r < 4; r++) {
                float v = sacc[sb][r] * 0.125f;   // 1/sqrt(64)
                if (diag) {
                    int kv = s0 + sb * 16 + 4 * g + r;
                    int qg = qbase + w * 16 + r4;
                    if (kv > qg) v = -1e30f;
                }
                p[sb][r] = v;
                mx = fmaxf(mx, v);
            }
        mx = fmaxf(mx, __shfl_xor(mx, 16, 64));
        mx = fmaxf(mx, __shfl_xor(mx, 32, 64));
        float mnew = fmaxf(mrun, mx);
        float alpha = __expf(mrun - mnew);
        float rsum = 0.f;
#pragma unroll
        for (int sb = 0; sb < 4; sb++)
#pragma unroll
            for (int r = 0; r < 4; r++) {
                float e = __expf(p[sb][r] - mnew);
                p[sb][r] = e;
                rsum += e;
            }
        rsum += __shfl_xor(rsum, 16, 64);
        rsum += __shfl_xor(rsum, 32, 64);
        lrun = lrun * alpha + rsum;
        mrun = mnew;
        // alpha for yacc rows (q = 4g+r): fetch from lane with r4 == 4g+r
        float aC[4];
#pragma unroll
        for (int r = 0; r < 4; r++) aC[r] = __shfl(alpha, 4 * g + r, 64);
#pragma unroll
        for (int ni = 0; ni < 4; ni++)
#pragma unroll
            for (int r = 0; r < 4; r++) yacc[ni][r] *= aC[r];
        // ---- P[q=r4][kv] -> per-wave LDS (bf16, swizzled), 4x ds_write_b64
#pragma unroll
        for (int sb = 0; sb < 4; sb++) {
            s16x4 pk;
#pragma unroll
            for (int r = 0; r < 4; r++) pk[r] = f2bf(p[sb][r]);
            int off = (r4 * 128 + (sb * 16 + 4 * g) * 2) ^ ((r4 & 7) << 4);
            *(s16x4*)((char*)&Ps[w][0] + off) = pk;
        }
        // ---- Y += P V  (A = P from LDS, B = V^T rows from Vs)
#pragma unroll
        for (int kk = 0; kk < 2; kk++) {
            s16x8 pf = *(const s16x8*)((const char*)&Ps[w][0] +
                        ((r4 * 128 + kk * 64 + g * 16) ^ ((r4 & 7) << 4)));
#pragma unroll
            for (int ni = 0; ni < 4; ni++) {
                int vrow = ni * 16 + r4;
                s16x8 vb = *(const s16x8*)((const char*)&Vs[cur][0] +
                            ((vrow * 128 + kk * 64 + g * 16) ^ ((r4 & 7) << 4)));
                yacc[ni] = __builtin_amdgcn_mfma_f32_16x16x32_bf16(pf, vb, yacc[ni], 0, 0, 0);
            }
        }
        VMCNT0;          // next-tile staging landed
        __syncthreads(); // all waves done with buf[cur]; buf[cur^1] visible
    }
    // epilogue: y[b, q, h*64+d], lane's yacc rows are q = 4g+r -> fetch lrun from lane r4==4g+r
    float lC[4];
#pragma unroll
    for (int r = 0; r < 4; r++) lC[r] = __shfl(lrun, 4 * g + r, 64);
    int bb = bh >> 4, h = bh & 15;
#pragma unroll
    for (int ni = 0; ni < 4; ni++)
#pragma unroll
        for (int r = 0; r < 4; r++) {
            int q = qbase + w * 16 + 4 * g + r;
            y[((size_t)bb * T_SEQ + q) * C_DIM + h * HD + ni * 16 + r4] = yacc[ni][r] / lC[r];
        }
}

extern "C" void kernel_launch(void* const* d_in, const int* in_sizes, int n_in,
                              void* d_out, int out_size, void* d_ws, size_t ws_size,
                              hipStream_t stream) {
    (void)in_sizes; (void)n_in; (void)out_size; (void)ws_size;
    const float* x    = (const float*)d_in[0];
    const float* wq   = (const float*)d_in[1];
    const float* bq   = (const float*)d_in[2];
    const float* wk   = (const float*)d_in[3];
    const float* bk   = (const float*)d_in[4];
    const float* wvp  = (const float*)d_in[5];
    const float* bv   = (const float*)d_in[6];
    const float* ln1w = (const float*)d_in[7];
    const float* ln1b = (const float*)d_in[8];
    const float* ln2w = (const float*)d_in[9];
    const float* ln2b = (const float*)d_in[10];
    const float* wfc  = (const float*)d_in[11];
    const float* bfc  = (const float*)d_in[12];
    const float* wpr  = (const float*)d_in[13];
    const float* bpr  = (const float*)d_in[14];

    float* xout = (float*)d_out;                 // [2,2048,1024]
    float* kout = xout + 4194304;                // [2,16,2048,64]
    float* vout = kout + 4194304;                // [2,16,2048,64]

    // workspace layout (bf16 region then fp32 region), ~126 MB total
    short* wqkvt = (short*)d_ws;                 // [3072][1024] bf16 (q rows 0-1023, k, v)
    short* wfct  = wqkvt + 3072 * 1024;          // [4096][1024]
    short* wprt  = wfct + 4096 * 1024;           // [1024][4096]
    short* hb    = wprt + 1024 * 4096;           // LN1 out bf16 [4096][1024]
    short* qb    = hb + 4096 * 1024;             // Q bf16 [B,H,T,D]
    short* kbuf  = qb + 4096 * 1024;             // K bf16 [B,H,T,D]
    short* vtb   = kbuf + 4096 * 1024;           // V bf16 transposed [B,H,D,T]
    short* h2b   = vtb + 4096 * 1024;            // LN2 out bf16
    short* fcb   = h2b + 4096 * 1024;            // gelu(fc) bf16 [4096][4096]
    float* ybuf  = (float*)(fcb + 4096 * 4096);  // attn out fp32 [4096][1024]
    float* x1    = ybuf + 4096 * 1024;           // x + y fp32

    dim3 tb(32, 8);
    transpose_cast_kernel<<<dim3(32, 32),  tb, 0, stream>>>(wq,  wqkvt,                1024, 1024);
    transpose_cast_kernel<<<dim3(32, 32),  tb, 0, stream>>>(wk,  wqkvt + 1024 * 1024,  1024, 1024);
    transpose_cast_kernel<<<dim3(32, 32),  tb, 0, stream>>>(wvp, wqkvt + 2048 * 1024,  1024, 1024);
    transpose_cast_kernel<<<dim3(128, 32), tb, 0, stream>>>(wfc, wfct,                 1024, 4096);
    transpose_cast_kernel<<<dim3(32, 128), tb, 0, stream>>>(wpr, wprt,                 4096, 1024);

    ln_kernel<<<4096, 256, 0, stream>>>(x, ln1w, ln1b, hb);

    // fused QKV GEMM: M=4096, N=3072, K=1024 — 256^2 tile, grid 16x12 = 192 (%8==0)
    gemm_kp<256, 256, 2, 4, 0><<<dim3(16, 12), 512, 0, stream>>>(hb, wqkvt, 1024, 3072,
        bq, bk, bv, qb, kbuf, vtb, kout, vout, nullptr);

    attn_kernel<<<dim3(32, 32), 256, 0, stream>>>(qb, kbuf, vtb, ybuf);

    resln_kernel<<<4096, 256, 0, stream>>>(x, ybuf, ln2w, ln2b, x1, h2b);

    // MLP fc + gelu: M=4096, N=4096, K=1024 — 256^2 tile, grid 16x16 = 256
    gemm_kp<256, 256, 2, 4, 1><<<dim3(16, 16), 512, 0, stream>>>(h2b, wfct, 1024, 4096,
        bfc, nullptr, nullptr, fcb, nullptr, nullptr, nullptr, nullptr, nullptr);

    // MLP proj + bias + residual: M=4096, N=1024, K=4096 — 128^2 tile, 8 waves, grid 32x8 = 256
    gemm_kp<128, 128, 2, 4, 2><<<dim3(32, 8), 512, 0, stream>>>(fcb, wprt, 4096, 1024,
        bpr, nullptr, nullptr, nullptr, nullptr, nullptr, xout, nullptr, x1);
}

// Round 7
// 315.035 us; speedup vs baseline: 1.0039x; 1.0039x over previous
//
#include <hip/hip_runtime.h>
#include <hip/hip_bf16.h>

// Transformer block fwd: B=2, T=2048, C=1024, H=16, D=64.
// out = concat(x_out fp32 [2,2048,1024], k fp32 [2,16,2048,64], v fp32 [2,16,2048,64])

#define T_SEQ 2048
#define C_DIM 1024
#define HEADS 16
#define HD    64

typedef __attribute__((ext_vector_type(8))) short s16x8;   // 8 x bf16 (4 VGPR) — MFMA A/B frag
typedef __attribute__((ext_vector_type(4))) short s16x4;
typedef __attribute__((ext_vector_type(4))) float f32x4;   // MFMA C/D frag

__device__ __forceinline__ short f2bf(float f) {
    union { __hip_bfloat16 h; short s; } u;
    u.h = __float2bfloat16(f);
    return u.s;
}

// async global->LDS, 16B per lane. LDS dest = wave-uniform base + lane*16 (linear).
__device__ __forceinline__ void gload16(const void* g, void* l) {
    __builtin_amdgcn_global_load_lds(
        (const __attribute__((address_space(1))) void*)g,
        (__attribute__((address_space(3))) void*)l, 16, 0, 0);
}
#define VMCNT0 asm volatile("s_waitcnt vmcnt(0)" ::: "memory")
#define BARRAW asm volatile("s_barrier" ::: "memory")
#define PRIO1  __builtin_amdgcn_s_setprio(1)
#define PRIO0  __builtin_amdgcn_s_setprio(0)

template<int N> __device__ __forceinline__ void vmcnt_n() {
    asm volatile("s_waitcnt vmcnt(%0)" :: "n"(N) : "memory");
}

// ---------------- weight transpose + cast: W[K][N] fp32 -> Wt[N][K] bf16 ----------------
__global__ __launch_bounds__(256) void transpose_cast_kernel(
    const float* __restrict__ W, short* __restrict__ Wt, int K, int N) {
    __shared__ float t[32][33];
    int n0 = blockIdx.x * 32, k0 = blockIdx.y * 32;
    int tx = threadIdx.x, ty = threadIdx.y;
#pragma unroll
    for (int i = 0; i < 4; i++) t[ty + 8 * i][tx] = W[(k0 + ty + 8 * i) * N + n0 + tx];
    __syncthreads();
#pragma unroll
    for (int i = 0; i < 4; i++) Wt[(n0 + ty + 8 * i) * K + k0 + tx] = f2bf(t[tx][ty + 8 * i]);
}

// ---------------- LayerNorm: one block per row of [4096][1024], bf16 out ----------------
__global__ __launch_bounds__(256) void ln_kernel(
    const float* __restrict__ x, const float* __restrict__ w, const float* __restrict__ b,
    short* __restrict__ out) {
    int row = blockIdx.x, tid = threadIdx.x;
    float4 v = ((const float4*)(x + row * C_DIM))[tid];
    float s  = v.x + v.y + v.z + v.w;
    float sq = v.x * v.x + v.y * v.y + v.z * v.z + v.w * v.w;
#pragma unroll
    for (int off = 32; off > 0; off >>= 1) {
        s  += __shfl_down(s, off, 64);
        sq += __shfl_down(sq, off, 64);
    }
    __shared__ float rs[4], rq[4];
    int wv = tid >> 6, ln = tid & 63;
    if (ln == 0) { rs[wv] = s; rq[wv] = sq; }
    __syncthreads();
    s = rs[0] + rs[1] + rs[2] + rs[3];
    sq = rq[0] + rq[1] + rq[2] + rq[3];
    float mean = s * (1.f / C_DIM);
    float rstd = rsqrtf(sq * (1.f / C_DIM) - mean * mean + 1e-5f);
    float4 wv4 = ((const float4*)w)[tid];
    float4 bv4 = ((const float4*)b)[tid];
    s16x4 o;
    o[0] = f2bf((v.x - mean) * rstd * wv4.x + bv4.x);
    o[1] = f2bf((v.y - mean) * rstd * wv4.y + bv4.y);
    o[2] = f2bf((v.z - mean) * rstd * wv4.z + bv4.z);
    o[3] = f2bf((v.w - mean) * rstd * wv4.w + bv4.w);
    *(s16x4*)(out + row * C_DIM + tid * 4) = o;
}

// ---- residual + LN2 + PROJ-output init: xout = x+y+b_proj (fp32), h2 = LN(x+y) bf16 ----
__global__ __launch_bounds__(256) void resln_kernel(
    const float* __restrict__ x, const float* __restrict__ y,
    const float* __restrict__ w, const float* __restrict__ b,
    const float* __restrict__ bproj,
    short* __restrict__ out, float* __restrict__ xout) {
    int row = blockIdx.x, tid = threadIdx.x;
    float4 vx = ((const float4*)(x + row * C_DIM))[tid];
    float4 vy = ((const float4*)(y + row * C_DIM))[tid];
    float4 v;
    v.x = vx.x + vy.x; v.y = vx.y + vy.y; v.z = vx.z + vy.z; v.w = vx.w + vy.w;
    float4 bp = ((const float4*)bproj)[tid];
    float4 xo;
    xo.x = v.x + bp.x; xo.y = v.y + bp.y; xo.z = v.z + bp.z; xo.w = v.w + bp.w;
    ((float4*)(xout + row * C_DIM))[tid] = xo;   // PROJ GEMM atomically adds onto this
    float s  = v.x + v.y + v.z + v.w;
    float sq = v.x * v.x + v.y * v.y + v.z * v.z + v.w * v.w;
#pragma unroll
    for (int off = 32; off > 0; off >>= 1) {
        s  += __shfl_down(s, off, 64);
        sq += __shfl_down(sq, off, 64);
    }
    __shared__ float rs[4], rq[4];
    int wv = tid >> 6, ln = tid & 63;
    if (ln == 0) { rs[wv] = s; rq[wv] = sq; }
    __syncthreads();
    s = rs[0] + rs[1] + rs[2] + rs[3];
    sq = rq[0] + rq[1] + rq[2] + rq[3];
    float mean = s * (1.f / C_DIM);
    float rstd = rsqrtf(sq * (1.f / C_DIM) - mean * mean + 1e-5f);
    float4 wv4 = ((const float4*)w)[tid];
    float4 bv4 = ((const float4*)b)[tid];
    s16x4 o;
    o[0] = f2bf((v.x - mean) * rstd * wv4.x + bv4.x);
    o[1] = f2bf((v.y - mean) * rstd * wv4.y + bv4.y);
    o[2] = f2bf((v.z - mean) * rstd * wv4.z + bv4.z);
    o[3] = f2bf((v.w - mean) * rstd * wv4.w + bv4.w);
    *(s16x4*)(out + row * C_DIM + tid * 4) = o;
}

// ---------------- phase-interleaved GEMM, R5-proven schedule + counted vmcnt ----------------
// C = A[M,K-chunk](bf16, row stride LDA) @ Bt[N,K-chunk]^T + epilogue. BK=64, 8 waves (2Mx4N),
// wave tile 128x64, double-buffered LDS (128 KB). 4 phases/K-tile, quadrants (0,0)(1,0)(1,1)(0,1).
// Staging calendar (R5, empirically race-clean): P1: A0'+B0', P2: A1', P3: B1'; waits vmcnt(3R)
// after P1/P2, vmcnt(2R) after P4; tail peels R -> 0. Pre-swizzled gload source, linear LDS dest,
// XOR-swizzled ds_read_b128.
// MODE 0: fused QKV; MODE 1: FC+GELU; MODE 2: split-K partial, atomicAdd into of0 (no bias).
template<int BM, int BN, int WMG, int WNG, int MODE>
__global__ __launch_bounds__(WMG * WNG * 64, 2) void gemm_kp(
    const short* __restrict__ A, const short* __restrict__ Bt,
    int K, int LDA, int N,
    const float* __restrict__ b0, const float* __restrict__ b1, const float* __restrict__ b2,
    short* __restrict__ os0, short* __restrict__ os1, short* __restrict__ os2,
    float* __restrict__ of0) {
    constexpr int THREADS = WMG * WNG * 64;
    constexpr int R = (BM * 64) / (16 * THREADS);   // gload rounds per half-tile (=2)
    constexpr int RROWS = THREADS / 8;              // rows per round (=64)
    constexpr int WTM = BM / WMG, WTN = BN / WNG;   // 128 x 64
    constexpr int MFR = WTM / 16, NFR = WTN / 16;   // 8 x 4
    constexpr int MH = MFR / 2, NH = NFR / 2;       // 4 x 2

    __shared__ short As[2][BM * 64];
    __shared__ short Bs[2][BN * 64];

    const int tid = threadIdx.x;
    const int wv = tid >> 6, lane = tid & 63, g = lane >> 4, r4 = lane & 15;
    const int wm = wv / WNG, wn = wv % WNG;
    const int lr = lane >> 3, lc = lane & 7, sc = lc ^ lr;

    const int nwg = gridDim.x * gridDim.y;
    const int bid = blockIdx.y * gridDim.x + blockIdx.x;
    const int swz = (bid & 7) * (nwg >> 3) + (bid >> 3);   // bijective, nwg % 8 == 0
    const int m0 = (swz % gridDim.x) * BM;
    const int yy = swz / gridDim.x;
    int n0, kch;
    if constexpr (MODE == 2) {
        kch = yy >> 2;            // split-K chunk (4 chunks of K)
        n0 = (yy & 3) * BN;       // N / BN = 1024/256 = 4
    } else {
        kch = 0;
        n0 = yy * BN;
    }
    const size_t kbase = (size_t)kch * K;
    const size_t aoff = (size_t)m0 * LDA + kbase + sc * 8;
    const size_t boff = (size_t)n0 * LDA + kbase + sc * 8;

    const f32x4 zero4 = {0.f, 0.f, 0.f, 0.f};
    f32x4 acc[MFR][NFR];
#pragma unroll
    for (int i = 0; i < MFR; i++)
#pragma unroll
        for (int j = 0; j < NFR; j++) acc[i][j] = zero4;

    s16x8 aF[MH][2], bF[NH][2];

    auto stA = [&](int bb, int t1, int h) {
#pragma unroll
        for (int j = 0; j < R; j++) {
            int rbase = h * (BM / 2) + j * RROWS + wv * 8;
            gload16(A + aoff + (size_t)(rbase + lr) * LDA + (size_t)t1 * 64, &As[bb][rbase * 64]);
        }
    };
    auto stB = [&](int bb, int t1, int h) {
#pragma unroll
        for (int j = 0; j < R; j++) {
            int rbase = h * (BN / 2) + j * RROWS + wv * 8;
            gload16(Bt + boff + (size_t)(rbase + lr) * LDA + (size_t)t1 * 64, &Bs[bb][rbase * 64]);
        }
    };
    auto ldA = [&](const char* Ac, int h) {
#pragma unroll
        for (int mf = 0; mf < MH; mf++) {
            int row = wm * WTM + (h * MH + mf) * 16 + r4;
#pragma unroll
            for (int kk = 0; kk < 2; kk++)
                aF[mf][kk] = *(const s16x8*)(Ac + ((row * 128 + kk * 64 + g * 16) ^ ((row & 7) << 4)));
        }
    };
    auto ldB = [&](const char* Bc, int h) {
#pragma unroll
        for (int nf = 0; nf < NH; nf++) {
            int row = wn * WTN + (h * NH + nf) * 16 + r4;
#pragma unroll
            for (int kk = 0; kk < 2; kk++)
                bF[nf][kk] = *(const s16x8*)(Bc + ((row * 128 + kk * 64 + g * 16) ^ ((row & 7) << 4)));
        }
    };

#define MMQ(QM, QN)                                                                  \
    PRIO1;                                                                           \
    _Pragma("unroll")                                                                \
    for (int mf = 0; mf < MH; mf++)                                                  \
        _Pragma("unroll")                                                            \
        for (int nf = 0; nf < NH; nf++)                                              \
            _Pragma("unroll")                                                        \
            for (int kk = 0; kk < 2; kk++)                                           \
                acc[(QM) * MH + mf][(QN) * NH + nf] =                                \
                    __builtin_amdgcn_mfma_f32_16x16x32_bf16(                         \
                        aF[mf][kk], bF[nf][kk], acc[(QM) * MH + mf][(QN) * NH + nf], \
                        0, 0, 0);                                                    \
    PRIO0;

    // prologue: stage K-tile 0 fully into buffer 0, drain, barrier
    stA(0, 0, 0); stB(0, 0, 0); stA(0, 0, 1); stB(0, 0, 1);
    VMCNT0;
    BARRAW;

    const int NT = K >> 6;
    for (int t = 0; t < NT; ++t) {
        const int c = t & 1, bb = c ^ 1;
        const bool st = (t + 1 < NT);
        const char* Ac = (const char*)&As[c][0];
        const char* Bc = (const char*)&Bs[c][0];

        // phase 1: read B0 + A0; stage (t+1).A0 + (t+1).B0
        ldB(Bc, 0);
        ldA(Ac, 0);
        if (st) { stA(bb, t + 1, 0); stB(bb, t + 1, 0); }
        BARRAW;
        MMQ(0, 0);
        if (st) vmcnt_n<3 * R>(); else vmcnt_n<R>();
        BARRAW;

        // phase 2: read A1; stage (t+1).A1
        ldA(Ac, 1);
        if (st) stA(bb, t + 1, 1);
        BARRAW;
        MMQ(1, 0);
        if (st) vmcnt_n<3 * R>(); else vmcnt_n<0>();
        BARRAW;

        // phase 3: read B1; stage (t+1).B1   (aF half1 held in regs)
        ldB(Bc, 1);
        if (st) stB(bb, t + 1, 1);
        BARRAW;
        MMQ(1, 1);
        BARRAW;

        // phase 4: re-read A0   (bF half1 held in regs)
        ldA(Ac, 0);
        BARRAW;
        MMQ(0, 1);
        if (st) vmcnt_n<2 * R>();
        BARRAW;
    }
#undef MMQ

    // epilogue: D layout col = lane&15, row = 4*(lane>>4)+r  [verified m89/m91]
#pragma unroll
    for (int mf = 0; mf < MFR; mf++) {
#pragma unroll
        for (int nf = 0; nf < NFR; nf++) {
            int n = n0 + wn * WTN + nf * 16 + r4;
#pragma unroll
            for (int r = 0; r < 4; r++) {
                int m = m0 + wm * WTM + mf * 16 + 4 * g + r;
                float val = acc[mf][nf][r];
                if constexpr (MODE == 0) {
                    int sel = n >> 10, nn = n & 1023;
                    const float* bp = (sel == 0) ? b0 : ((sel == 1) ? b1 : b2);
                    val += bp[nn];
                    int bb2 = m >> 11, tt = m & 2047, h = nn >> 6, d = nn & 63;
                    int qi = ((bb2 * HEADS + h) * T_SEQ + tt) * HD + d;
                    if (sel == 0) {
                        os0[qi] = f2bf(val);
                    } else if (sel == 1) {
                        os1[qi] = f2bf(val);
                        of0[qi] = val;                   // kout
                    } else {
                        of0[4194304 + qi] = val;        // vout
                        os2[((bb2 * HEADS + h) * HD + d) * T_SEQ + tt] = f2bf(val);
                    }
                } else if constexpr (MODE == 1) {
                    val += b0[n];
                    val = 0.5f * val * (1.f + erff(val * 0.70710678118f));  // exact GELU
                    os0[m * N + n] = f2bf(val);
                } else {
                    atomicAdd(&of0[(size_t)m * N + n], val);  // onto x+y+b_proj init
                }
            }
        }
    }
}

// ---------------- causal flash attention (swapped QK^T, lane-local softmax) ----------------
__global__ __launch_bounds__(256) void attn_kernel(
    const short* __restrict__ qb, const short* __restrict__ kb,
    const short* __restrict__ vtb, float* __restrict__ y) {
    __shared__ short Ks[2][64 * 64];
    __shared__ short Vs[2][64 * 64];
    __shared__ short Ps[4][16 * 64];
    int qtr = (gridDim.x - 1) - blockIdx.x;
    int bh = blockIdx.y;
    int tid = threadIdx.x, w = tid >> 6, lane = tid & 63, g = lane >> 4, r4 = lane & 15;
    int qbase = qtr * 64;
    int lr = lane >> 3, lc = lane & 7, sc = lc ^ lr;

    const short* Qp = qb + ((size_t)bh * T_SEQ + qbase + w * 16 + r4) * HD;
    s16x8 qf0 = *(const s16x8*)&Qp[g * 8];
    s16x8 qf1 = *(const s16x8*)&Qp[32 + g * 8];

    const f32x4 zero4 = {0.f, 0.f, 0.f, 0.f};
    f32x4 yacc[4];
#pragma unroll
    for (int ni = 0; ni < 4; ni++) yacc[ni] = zero4;
    float mrun = -1e30f, lrun = 0.f;

#pragma unroll
    for (int j = 0; j < 2; j++) {
        int rw = (w * 2 + j) * 8 + lr;
        gload16(kb  + ((size_t)bh * T_SEQ + rw) * HD + sc * 8, &Ks[0][(w * 2 + j) * 512]);
        gload16(vtb + ((size_t)bh * HD + rw) * T_SEQ + sc * 8, &Vs[0][(w * 2 + j) * 512]);
    }
    VMCNT0;
    __syncthreads();

    int nst = qtr + 1;
    for (int st = 0; st < nst; ++st) {
        int cur = st & 1;
        int s0 = st * 64;
        if (st + 1 < nst) {
#pragma unroll
            for (int j = 0; j < 2; j++) {
                int rw = (w * 2 + j) * 8 + lr;
                gload16(kb  + ((size_t)bh * T_SEQ + s0 + 64 + rw) * HD + sc * 8,
                        &Ks[cur ^ 1][(w * 2 + j) * 512]);
                gload16(vtb + ((size_t)bh * HD + rw) * T_SEQ + s0 + 64 + sc * 8,
                        &Vs[cur ^ 1][(w * 2 + j) * 512]);
            }
        }
        f32x4 sacc[4];
#pragma unroll
        for (int sb = 0; sb < 4; sb++) sacc[sb] = zero4;
#pragma unroll
        for (int kk = 0; kk < 2; kk++) {
            s16x8 qf = (kk == 0) ? qf0 : qf1;
#pragma unroll
            for (int sb = 0; sb < 4; sb++) {
                int srow = sb * 16 + r4;
                s16x8 kf = *(const s16x8*)((const char*)&Ks[cur][0] +
                            ((srow * 128 + kk * 64 + g * 16) ^ ((r4 & 7) << 4)));
                sacc[sb] = __builtin_amdgcn_mfma_f32_16x16x32_bf16(kf, qf, sacc[sb], 0, 0, 0);
            }
        }
        bool diag = (st == qtr);
        float p[4][4];
        float mx = -1e30f;
#pragma unroll
        for (int sb = 0; sb < 4; sb++)
#pragma unroll
            for (int r = 0; r < 4; r++) {
                float v = sacc[sb][r] * 0.125f;
                if (diag) {
                    int kv = s0 + sb * 16 + 4 * g + r;
                    int qg = qbase + w * 16 + r4;
                    if (kv > qg) v = -1e30f;
                }
                p[sb][r] = v;
                mx = fmaxf(mx, v);
            }
        mx = fmaxf(mx, __shfl_xor(mx, 16, 64));
        mx = fmaxf(mx, __shfl_xor(mx, 32, 64));
        float mnew = fmaxf(mrun, mx);
        float alpha = __expf(mrun - mnew);
        float rsum = 0.f;
#pragma unroll
        for (int sb = 0; sb < 4; sb++)
#pragma unroll
            for (int r = 0; r < 4; r++) {
                float e = __expf(p[sb][r] - mnew);
                p[sb][r] = e;
                rsum += e;
            }
        rsum += __shfl_xor(rsum, 16, 64);
        rsum += __shfl_xor(rsum, 32, 64);
        lrun = lrun * alpha + rsum;
        mrun = mnew;
        float aC[4];
#pragma unroll
        for (int r = 0; r < 4; r++) aC[r] = __shfl(alpha, 4 * g + r, 64);
#pragma unroll
        for (int ni = 0; ni < 4; ni++)
#pragma unroll
            for (int r = 0; r < 4; r++) yacc[ni][r] *= aC[r];
#pragma unroll
        for (int sb = 0; sb < 4; sb++) {
            s16x4 pk;
#pragma unroll
            for (int r = 0; r < 4; r++) pk[r] = f2bf(p[sb][r]);
            int off = (r4 * 128 + (sb * 16 + 4 * g) * 2) ^ ((r4 & 7) << 4);
            *(s16x4*)((char*)&Ps[w][0] + off) = pk;
        }
#pragma unroll
        for (int kk = 0; kk < 2; kk++) {
            s16x8 pf = *(const s16x8*)((const char*)&Ps[w][0] +
                        ((r4 * 128 + kk * 64 + g * 16) ^ ((r4 & 7) << 4)));
#pragma unroll
            for (int ni = 0; ni < 4; ni++) {
                int vrow = ni * 16 + r4;
                s16x8 vb = *(const s16x8*)((const char*)&Vs[cur][0] +
                            ((vrow * 128 + kk * 64 + g * 16) ^ ((r4 & 7) << 4)));
                yacc[ni] = __builtin_amdgcn_mfma_f32_16x16x32_bf16(pf, vb, yacc[ni], 0, 0, 0);
            }
        }
        VMCNT0;
        __syncthreads();
    }
    float lC[4];
#pragma unroll
    for (int r = 0; r < 4; r++) lC[r] = __shfl(lrun, 4 * g + r, 64);
    int bb = bh >> 4, h = bh & 15;
#pragma unroll
    for (int ni = 0; ni < 4; ni++)
#pragma unroll
        for (int r = 0; r < 4; r++) {
            int q = qbase + w * 16 + 4 * g + r;
            y[((size_t)bb * T_SEQ + q) * C_DIM + h * HD + ni * 16 + r4] = yacc[ni][r] / lC[r];
        }
}

extern "C" void kernel_launch(void* const* d_in, const int* in_sizes, int n_in,
                              void* d_out, int out_size, void* d_ws, size_t ws_size,
                              hipStream_t stream) {
    (void)in_sizes; (void)n_in; (void)out_size; (void)ws_size;
    const float* x    = (const float*)d_in[0];
    const float* wq   = (const float*)d_in[1];
    const float* bq   = (const float*)d_in[2];
    const float* wk   = (const float*)d_in[3];
    const float* bk   = (const float*)d_in[4];
    const float* wvp  = (const float*)d_in[5];
    const float* bv   = (const float*)d_in[6];
    const float* ln1w = (const float*)d_in[7];
    const float* ln1b = (const float*)d_in[8];
    const float* ln2w = (const float*)d_in[9];
    const float* ln2b = (const float*)d_in[10];
    const float* wfc  = (const float*)d_in[11];
    const float* bfc  = (const float*)d_in[12];
    const float* wpr  = (const float*)d_in[13];
    const float* bpr  = (const float*)d_in[14];

    float* xout = (float*)d_out;                 // [2,2048,1024]
    float* kout = xout + 4194304;                // [2,16,2048,64] (vout = kout + 4194304)

    // workspace layout (~124 MB)
    short* wqkvt = (short*)d_ws;                 // [3072][1024] bf16
    short* wfct  = wqkvt + 3072 * 1024;          // [4096][1024]
    short* wprt  = wfct + 4096 * 1024;           // [1024][4096]
    short* hb    = wprt + 1024 * 4096;           // LN1 out bf16 [4096][1024]
    short* qb    = hb + 4096 * 1024;             // Q bf16 [B,H,T,D]
    short* kbuf  = qb + 4096 * 1024;             // K bf16 [B,H,T,D]
    short* vtb   = kbuf + 4096 * 1024;           // V bf16 transposed [B,H,D,T]
    short* h2b   = vtb + 4096 * 1024;            // LN2 out bf16
    short* fcb   = h2b + 4096 * 1024;            // gelu(fc) bf16 [4096][4096]
    float* ybuf  = (float*)(fcb + 4096 * 4096);  // attn out fp32 [4096][1024]

    dim3 tb(32, 8);
    transpose_cast_kernel<<<dim3(32, 32),  tb, 0, stream>>>(wq,  wqkvt,                1024, 1024);
    transpose_cast_kernel<<<dim3(32, 32),  tb, 0, stream>>>(wk,  wqkvt + 1024 * 1024,  1024, 1024);
    transpose_cast_kernel<<<dim3(32, 32),  tb, 0, stream>>>(wvp, wqkvt + 2048 * 1024,  1024, 1024);
    transpose_cast_kernel<<<dim3(128, 32), tb, 0, stream>>>(wfc, wfct,                 1024, 4096);
    transpose_cast_kernel<<<dim3(32, 128), tb, 0, stream>>>(wpr, wprt,                 4096, 1024);

    ln_kernel<<<4096, 256, 0, stream>>>(x, ln1w, ln1b, hb);

    // fused QKV GEMM: M=4096, N=3072, K=1024 — grid 16x12 = 192
    gemm_kp<256, 256, 2, 4, 0><<<dim3(16, 12), 512, 0, stream>>>(hb, wqkvt, 1024, 1024, 3072,
        bq, bk, bv, qb, kbuf, vtb, kout);

    attn_kernel<<<dim3(32, 32), 256, 0, stream>>>(qb, kbuf, vtb, ybuf);

    // x+y residual, LN2, and xout init (= x+y+b_proj)
    resln_kernel<<<4096, 256, 0, stream>>>(x, ybuf, ln2w, ln2b, bpr, h2b, xout);

    // MLP fc + gelu: M=4096, N=4096, K=1024 — grid 16x16 = 256
    gemm_kp<256, 256, 2, 4, 1><<<dim3(16, 16), 512, 0, stream>>>(h2b, wfct, 1024, 1024, 4096,
        bfc, nullptr, nullptr, fcb, nullptr, nullptr, nullptr);

    // MLP proj, split-K=4 (K-chunks of 1024), atomicAdd into xout — grid 16x16 = 256
    gemm_kp<256, 256, 2, 4, 2><<<dim3(16, 16), 512, 0, stream>>>(fcb, wprt, 1024, 4096, 1024,
        nullptr, nullptr, nullptr, nullptr, nullptr, nullptr, xout);
}